// Round 13
// baseline (111.881 us; speedup 1.0000x reference)
//
#include <hip/hip_runtime.h>
#include <math.h>

#define D 256
#define NRULES 1024
#define KMAX 16   // bucket stride; slot>=KMAX spills (P ~ 0 at Poisson(2))
#define NSPILLBLK 64

// ---------------- prep: parallel histogram, no scan ----------------
__global__ void prep_kernel(const int* __restrict__ token_ids,
                            const int* __restrict__ token_rules,
                            int ntok,
                            int* __restrict__ counts,     // [NRULES] pre-zeroed
                            int* __restrict__ bucket,     // [NRULES*KMAX]
                            int* __restrict__ spill_tok,  // [ntok]
                            int* __restrict__ spill_rule, // [ntok]
                            int* __restrict__ nspill) {   // [1] pre-zeroed
    const int i = blockIdx.x * blockDim.x + threadIdx.x;
    if (i >= ntok) return;
    const int r = token_rules[token_ids[i]];
    const int slot = atomicAdd(&counts[r], 1);
    if (slot < KMAX) {
        bucket[r * KMAX + slot] = i;
    } else {
        const int k = atomicAdd(nspill, 1);
        spill_tok[k]  = i;
        spill_rule[k] = r;
    }
}

// ---------------- single full-matrix pass applying to CR tokens ----------------
// R5 inner structure: 4 waves, wave = 64-col quarter, rr = lane>>4 row subgroup
// (rows 4i+rr); the 4 waves consume full 1KB rows in lockstep.
template <int CR>
__device__ __forceinline__ void apply_rule(
    const float* __restrict__ M,
    const float* __restrict__ hidden,
    const int*   __restrict__ toks,    // LDS, ntk entries (ntk <= CR)
    int ntk,
    int wave, int lane, int rr, int col,
    float (*__restrict__ h_lds)[D], float* __restrict__ sq_lds,
    float* __restrict__ out)
{
    // stage h rows as float4: wave j stages token row j (64 lanes x 16B = 1KB)
    for (int j = wave; j < CR; j += 4) {
        float4 v = {0.f, 0.f, 0.f, 0.f};
        if (j < ntk)
            v = *reinterpret_cast<const float4*>(
                &hidden[(size_t)toks[j] * D + (lane << 2)]);
        *reinterpret_cast<float4*>(&h_lds[j][lane << 2]) = v;
    }
    __syncthreads();

    float4 acc[CR];
    #pragma unroll
    for (int j = 0; j < CR; ++j) acc[j] = float4{0.f, 0.f, 0.f, 0.f};
    float s0 = 0.f, s1 = 0.f, s2 = 0.f, s3 = 0.f;  // independent fro chains

    #pragma unroll 8
    for (int i = 0; i < 64; ++i) {
        const int d = (i << 2) + rr;
        const float4 m = *reinterpret_cast<const float4*>(M + (size_t)d * D + col);
        s0 = fmaf(m.x, m.x, s0);
        s1 = fmaf(m.y, m.y, s1);
        s2 = fmaf(m.z, m.z, s2);
        s3 = fmaf(m.w, m.w, s3);
        #pragma unroll
        for (int j = 0; j < CR; ++j) {
            const float h = h_lds[j][d];  // 4 addrs/wave, x16 broadcast — conflict-free
            acc[j].x = fmaf(h, m.x, acc[j].x);
            acc[j].y = fmaf(h, m.y, acc[j].y);
            acc[j].z = fmaf(h, m.z, acc[j].z);
            acc[j].w = fmaf(h, m.w, acc[j].w);
        }
    }

    // Frobenius over the full matrix: wave reduce, park per wave
    float sq = (s0 + s1) + (s2 + s3);
    #pragma unroll
    for (int off = 32; off > 0; off >>= 1)
        sq += __shfl_down(sq, off, 64);
    if (lane == 0) sq_lds[wave] = sq;

    // butterfly over the 4 row-subgroups: every lane gets full column sums
    #pragma unroll
    for (int j = 0; j < CR; ++j) {
        #pragma unroll
        for (int mask = 16; mask < 64; mask <<= 1) {
            acc[j].x += __shfl_xor(acc[j].x, mask, 64);
            acc[j].y += __shfl_xor(acc[j].y, mask, 64);
            acc[j].z += __shfl_xor(acc[j].z, mask, 64);
            acc[j].w += __shfl_xor(acc[j].w, mask, 64);
        }
    }
    __syncthreads();  // sq_lds visible

    const float fro2 = sq_lds[0] + sq_lds[1] + sq_lds[2] + sq_lds[3];
    const float inv  = 1.0f / fmaxf(sqrtf(fro2), 1e-12f);

    // subgroup (j&3) writes token j's quarter (16 lanes x 16B contiguous)
    #pragma unroll
    for (int j = 0; j < CR; ++j) {
        if (j < ntk && rr == (j & 3)) {
            const int tok = toks[j];
            float4 o;
            o.x = acc[j].x * inv; o.y = acc[j].y * inv;
            o.z = acc[j].z * inv; o.w = acc[j].w * inv;
            *reinterpret_cast<float4*>(&out[(size_t)tok * D + col]) = o;
        }
    }
}

// ---------------- process: block b = (rule b>>2, phase q=b&3) ----------------
// Block (r,q) applies rule r's matrix to bucket slots q, q+4, q+8, q+12.
// Siblings (r,0..3) stream the same 256KB concurrently -> L3 serves duplicates.
__global__ __launch_bounds__(256) void process_kernel(
    const float* __restrict__ hidden,     // [NTOK, D]
    const float* __restrict__ rules,      // [NRULES, D, D]
    const int*   __restrict__ counts,
    const int*   __restrict__ bucket,
    const int*   __restrict__ spill_tok,
    const int*   __restrict__ spill_rule,
    const int*   __restrict__ nspill,
    float* __restrict__ out)
{
    const int b    = blockIdx.x;
    const int t    = threadIdx.x;
    const int wave = t >> 6;
    const int lane = t & 63;
    const int rr   = lane >> 4;
    const int col  = (wave << 6) + ((lane & 15) << 2);

    __shared__ float h_lds[4][D];
    __shared__ float sq_lds[4];
    __shared__ int   toks[4];

    if (b < 4 * NRULES) {
        const int r   = b >> 2;
        const int q   = b & 3;
        const int cnt = min(counts[r], KMAX);
        const int ntk = (cnt > q) ? ((cnt - q + 3) >> 2) : 0;  // slots q,q+4,...
        if (ntk > 0) {
            if (t < ntk) toks[t] = bucket[r * KMAX + q + (t << 2)];
            __syncthreads();
            const float* __restrict__ M = rules + (size_t)r * D * D;
            switch (ntk) {
                case 1:  apply_rule<1>(M, hidden, toks, 1, wave, lane, rr, col, h_lds, sq_lds, out); break;
                case 2:  apply_rule<2>(M, hidden, toks, 2, wave, lane, rr, col, h_lds, sq_lds, out); break;
                case 3:  apply_rule<3>(M, hidden, toks, 3, wave, lane, rr, col, h_lds, sq_lds, out); break;
                default: apply_rule<4>(M, hidden, toks, 4, wave, lane, rr, col, h_lds, sq_lds, out); break;
            }
        }
    }

    // rare overflow tokens (count>KMAX): strided over all blocks, 1-token passes
    const int ns = nspill[0];
    for (int k = b; k < ns; k += gridDim.x) {
        __syncthreads();  // protect h_lds/sq_lds from any prior pass
        if (t == 0) toks[0] = spill_tok[k];
        __syncthreads();
        apply_rule<1>(rules + (size_t)spill_rule[k] * D * D, hidden, toks, 1,
                      wave, lane, rr, col, h_lds, sq_lds, out);
    }
}

// ---------------- launcher ----------------
extern "C" void kernel_launch(void* const* d_in, const int* in_sizes, int n_in,
                              void* d_out, int out_size, void* d_ws, size_t ws_size,
                              hipStream_t stream) {
    const float* hidden      = (const float*)d_in[0];
    const int*   token_ids   = (const int*)d_in[1];
    const float* rules       = (const float*)d_in[2];
    const int*   token_rules = (const int*)d_in[3];
    float*       out         = (float*)d_out;

    const int ntok = in_sizes[1];  // B*S

    int* ws         = (int*)d_ws;
    int* counts     = ws;                        // NRULES
    int* nspill     = ws + NRULES;               // 1 (padded to 8)
    int* bucket     = ws + NRULES + 8;           // NRULES*KMAX
    int* spill_tok  = bucket + NRULES * KMAX;    // ntok
    int* spill_rule = spill_tok + ntok;          // ntok

    hipMemsetAsync(counts, 0, (NRULES + 8) * sizeof(int), stream);
    prep_kernel<<<(ntok + 255) / 256, 256, 0, stream>>>(
        token_ids, token_rules, ntok, counts, bucket, spill_tok, spill_rule, nspill);
    process_kernel<<<4 * NRULES + NSPILLBLK, 256, 0, stream>>>(
        hidden, rules, counts, bucket, spill_tok, spill_rule, nspill, out);
}